// Round 5
// baseline (965.004 us; speedup 1.0000x reference)
//
#include <hip/hip_runtime.h>
#include <hip/hip_bf16.h>

// Problem dims
#define BB 64
#define TT 168
#define NN 64
#define FF 17
#define HID 128
#define GATES 512   // 4*HID
#define NLAYERS 4
#define NROWS (BB*TT)   // 10752

// Workspace layout (float offsets)
#define WS_W1SRC 0
#define WS_W1DST 32
#define WS_W2SRC 64
#define WS_W2DST 192
#define WS_BSUM  320                    // 4*512 -> ends 2368
#define WS_WD    2560                   // 17 (pad 32): W1 @ (W2 @ a2dst)
#define WS_WSV   2592                   // 17 (pad 32): W1 @ (W2 @ a2src)
#define WS_W12   2624                   // 17*128 = 2176: W1 @ W2
#define WS_WXG0T 4800                   // 512*20 (17 used): (W12 @ Wih0^T)^T rows
#define WS_XG    1395712                // NROWS*512 = 5505024
#define WS_HSEQ0 6900736                // 4 buffers of NROWS*HID
#define HSEQ_SZ  1376256

// LDS-only barrier: s_waitcnt lgkmcnt(0) + raw s_barrier (no vmcnt drain).
__device__ __forceinline__ void lds_barrier() {
    __asm__ volatile("" ::: "memory");
    __builtin_amdgcn_s_waitcnt(0xc07f);
    __builtin_amdgcn_s_barrier();
    __asm__ volatile("" ::: "memory");
}

// Pin a value into a VGPR: opaque redefinition blocks load-rematerialization
// across the asm memory clobbers in lds_barrier (round-4 bug: compiler
// re-loaded Whh from L2 every timestep, VGPR_Count=80 < the 128 needed).
__device__ __forceinline__ void pin_vgpr(float& v) {
    __asm__ volatile("" : "+v"(v));
}

__device__ __forceinline__ float fsig(float x) {
    return __builtin_amdgcn_rcpf(1.f + __expf(-x));
}
__device__ __forceinline__ float ftanh(float x) {
    float e = __expf(2.f * x);
    return 1.f - 2.f * __builtin_amdgcn_rcpf(e + 1.f);
}
__device__ __forceinline__ float bcast_lane(float v, int lane) {
    return __int_as_float(__builtin_amdgcn_readlane(__float_as_int(v), lane));
}

// ---------------- prep1: attention projection vectors + bias sums ----------------
__global__ void prep1(const float* __restrict__ W1, const float* __restrict__ a1,
                      const float* __restrict__ W2, const float* __restrict__ a2,
                      const float* __restrict__ bih, const float* __restrict__ bhh,
                      float* __restrict__ ws) {
    int tid = threadIdx.x;
    if (tid < 34) {
        int f = tid % FF, half = tid / FF;
        float acc = 0.f;
        for (int o = 0; o < HID; o++) acc += W1[f*HID + o] * a1[half*HID + o];
        ws[(half ? WS_W1DST : WS_W1SRC) + f] = acc;
    }
    {
        int k = tid & 127, half = tid >> 7;
        float acc = 0.f;
        for (int o = 0; o < HID; o++) acc += W2[k*HID + o] * a2[half*HID + o];
        ws[(half ? WS_W2DST : WS_W2SRC) + k] = acc;
    }
    for (int idx = tid; idx < NLAYERS*GATES; idx += 256) ws[WS_BSUM + idx] = bih[idx] + bhh[idx];
}

// ---------------- prep2: W12 = W1 @ W2 (17 x 128) ----------------
__global__ void prep2(const float* __restrict__ W1, const float* __restrict__ W2,
                      float* __restrict__ ws) {
    int f = blockIdx.x, o = threadIdx.x;
    float acc = 0.f;
    for (int k = 0; k < HID; k++) acc += W1[f*HID + k] * W2[k*HID + o];
    ws[WS_W12 + f*HID + o] = acc;
}

// ---------------- prep3: WD/WSV (17 each) + WXG0T (512 x 17, stride 20) ----------------
__global__ void prep3(const float* __restrict__ W1, const float* __restrict__ Wih0,
                      float* __restrict__ ws) {
    int idx = blockIdx.x * 256 + threadIdx.x;
    if (idx < 17) {
        int f = idx;
        float acc = 0.f;
        for (int k = 0; k < HID; k++) acc += W1[f*HID + k] * ws[WS_W2DST + k];
        ws[WS_WD + f] = acc;
    } else if (idx < 34) {
        int f = idx - 17;
        float acc = 0.f;
        for (int k = 0; k < HID; k++) acc += W1[f*HID + k] * ws[WS_W2SRC + k];
        ws[WS_WSV + f] = acc;
    } else if (idx < 34 + GATES*FF) {
        int e = idx - 34;
        int j = e % GATES, f = e / GATES;   // f < 17
        float acc = 0.f;
        for (int o = 0; o < HID; o++) acc += ws[WS_W12 + f*HID + o] * Wih0[j*HID + o];
        ws[WS_WXG0T + j*20 + f] = acc;
    }
}

// ---------------- K1: fused GAT1 + GAT2(site) -> Xg layer-0 directly ----------------
struct __align__(16) GatSmem {
    float attn[64*68];       // P2 writes rows (stride 68), P3 reads
    float xsT[FF*64];        // [f][n]
    float xbarT[FF*68];      // [f][i], stride 68
    float src1[64], dst1[64], rinv[64], att2[64];
    float xbar2[20];
    float part_x[FF*8];      // P5a partials
    unsigned long long adjbits[64];
};
// ~28.5 KB -> 5 blocks/CU

__global__ __launch_bounds__(256) void gat_fused(const float* __restrict__ x, const int* __restrict__ adj,
                                                 const float* __restrict__ ws,
                                                 float* __restrict__ Xg, const int* __restrict__ site_ptr) {
    __shared__ GatSmem sm;
    const int tid = threadIdx.x;
    const int tt = blockIdx.x, bb = blockIdx.y;
    const int site = site_ptr[0];
    const int r = bb*TT + tt;
    const float* xblk = x + (size_t)r * (NN*FF);

    // P0: x transposed into LDS, adjacency bitmasks
    for (int idx = tid; idx < NN*FF; idx += 256) {
        int n = idx / FF, f = idx % FF;
        sm.xsT[f*64 + n] = xblk[idx];
    }
    {
        int w = tid >> 6, lane = tid & 63;
        for (int rr = w*16; rr < w*16 + 16; rr++) {
            int val = adj[rr*64 + lane];
            unsigned long long m = __ballot(val > 0);
            if (lane == 0) sm.adjbits[rr] = m | (1ull << rr);
        }
    }
    lds_barrier();

    // P1: src1/dst1 = x . (W1 @ a1-halves)
    if (tid < 128) {
        int n = tid & 63, half = tid >> 6;
        const float* wv = ws + (half ? WS_W1DST : WS_W1SRC);
        float acc = 0.f;
        #pragma unroll
        for (int f = 0; f < FF; f++) acc += sm.xsT[f*64 + n] * wv[f];
        if (half) sm.dst1[n] = acc; else sm.src1[n] = acc;
    }
    lds_barrier();

    // P2: attention logits -> exp -> attn rows
    {
        int q = tid & 3, i = tid >> 2;
        unsigned long long ab = sm.adjbits[i];
        float si = sm.src1[i];
        float v[16];
        float vmax = -1e30f;
        #pragma unroll
        for (int u = 0; u < 16; u++) {
            int jj = q*16 + u;
            float e = si + sm.dst1[jj];
            float lv = fmaxf(e, 0.2f*e);
            lv = ((ab >> jj) & 1ull) ? lv : -1e9f;
            v[u] = lv;
            vmax = fmaxf(vmax, lv);
        }
        vmax = fmaxf(vmax, __shfl_xor(vmax, 1, 4));
        vmax = fmaxf(vmax, __shfl_xor(vmax, 2, 4));
        float s = 0.f;
        float* arow = &sm.attn[i*68];
        #pragma unroll
        for (int w = 0; w < 4; w++) {
            float4 pv;
            pv.x = __expf(v[w*4+0] - vmax);
            pv.y = __expf(v[w*4+1] - vmax);
            pv.z = __expf(v[w*4+2] - vmax);
            pv.w = __expf(v[w*4+3] - vmax);
            s += (pv.x + pv.y) + (pv.z + pv.w);
            *(float4*)(arow + q*16 + w*4) = pv;
        }
        s += __shfl_xor(s, 1, 4);
        s += __shfl_xor(s, 2, 4);
        if (q == 0) sm.rinv[i] = 1.f / s;
    }
    lds_barrier();

    // P3: xbarT[f][i] = (P @ X)[i][f] * rinv
    {
        int i = tid & 63, q = tid >> 6;
        const float* arow = &sm.attn[i*68];
        float acc[5] = {0.f,0.f,0.f,0.f,0.f};
        const int nf = (q == 0) ? 5 : 4;
        for (int j4 = 0; j4 < 16; j4++) {
            float4 a4 = *(const float4*)(arow + j4*4);
            #pragma unroll
            for (int u = 0; u < 5; u++) {
                if (u < nf) {
                    int f = q + 4*u;
                    float4 x4 = *(const float4*)(&sm.xsT[f*64 + j4*4]);
                    acc[u] += a4.x*x4.x + a4.y*x4.y + a4.z*x4.z + a4.w*x4.w;
                }
            }
        }
        float ri = sm.rinv[i];
        #pragma unroll
        for (int u = 0; u < 5; u++) {
            if (u < nf) sm.xbarT[(q + 4*u)*68 + i] = acc[u] * ri;
        }
    }
    lds_barrier();

    // P4' (wave 0): dst2[j] = xbar[j].WD ; src2 = xbar[site].WSV ; softmax -> att2
    if (tid < 64) {
        int jj = tid;
        float d = 0.f, sp = 0.f;
        #pragma unroll
        for (int f = 0; f < FF; f++) {
            float xv = sm.xbarT[f*68 + jj];
            float xs = sm.xbarT[f*68 + site];
            d  += xv * ws[WS_WD + f];
            sp += xs * ws[WS_WSV + f];
        }
        unsigned long long ab = sm.adjbits[site];
        float e = sp + d;
        float lv = fmaxf(e, 0.2f*e);
        lv = ((ab >> jj) & 1ull) ? lv : -1e9f;
        float m = lv;
        #pragma unroll
        for (int dd = 1; dd < 64; dd <<= 1) m = fmaxf(m, __shfl_xor(m, dd));
        float p = __expf(lv - m);
        float s = p;
        #pragma unroll
        for (int dd = 1; dd < 64; dd <<= 1) s += __shfl_xor(s, dd);
        sm.att2[jj] = p / s;
    }
    lds_barrier();

    // P5a: xbar2 partials
    if (tid < FF*8) {
        int f = tid >> 3, c = tid & 7;
        float p = 0.f;
        #pragma unroll
        for (int u = 0; u < 8; u++) {
            int i = c*8 + u;
            p += sm.att2[i] * sm.xbarT[f*68 + i];
        }
        sm.part_x[f*8 + c] = p;
    }
    lds_barrier();

    // P5b: reduce xbar2
    if (tid < FF) {
        float s = 0.f;
        #pragma unroll
        for (int c = 0; c < 8; c++) s += sm.part_x[tid*8 + c];
        sm.xbar2[tid] = s;
    }
    lds_barrier();

    // P6': Xg0[r][j] = xbar2 . WXG0T[j] + bsum0[j]
    {
        float xb[FF];
        #pragma unroll
        for (int f = 0; f < FF; f++) xb[f] = sm.xbar2[f];
        #pragma unroll
        for (int half = 0; half < 2; half++) {
            int j = tid + half*256;
            const float4* wp = (const float4*)(ws + WS_WXG0T + j*20);
            float4 w0 = wp[0], w1 = wp[1], w2 = wp[2], w3 = wp[3];
            float wlast = ws[WS_WXG0T + j*20 + 16];
            float acc = ws[WS_BSUM + j];
            acc += w0.x*xb[0] + w0.y*xb[1] + w0.z*xb[2] + w0.w*xb[3];
            acc += w1.x*xb[4] + w1.y*xb[5] + w1.z*xb[6] + w1.w*xb[7];
            acc += w2.x*xb[8] + w2.y*xb[9] + w2.z*xb[10] + w2.w*xb[11];
            acc += w3.x*xb[12] + w3.y*xb[13] + w3.z*xb[14] + w3.w*xb[15];
            acc += wlast*xb[16];
            Xg[(size_t)r*GATES + j] = acc;
        }
    }
}

// ---------------- K2: input GEMM (layers 1-3) ----------------
__global__ __launch_bounds__(512, 2) void lstm_ingemm(const float* __restrict__ in_seq,
                                                      const float* __restrict__ Wih_l,
                                                      const float* __restrict__ bsum_l,
                                                      float* __restrict__ Xg) {
    const int j = threadIdx.x;
    float w[128];
    {
        const float4* wr = (const float4*)(Wih_l + j*HID);
        #pragma unroll
        for (int k = 0; k < 32; k++) {
            float4 v = wr[k];
            w[4*k] = v.x; w[4*k+1] = v.y; w[4*k+2] = v.z; w[4*k+3] = v.w;
        }
    }
    #pragma unroll
    for (int k = 0; k < 128; k++) pin_vgpr(w[k]);
    const float bj = bsum_l[j];
    const int r0 = blockIdx.x * 16;
    for (int rr = 0; rr < 16; rr += 2) {
        int r = r0 + rr;
        const float4* x0 = (const float4*)(in_seq + (size_t)r*HID);
        const float4* x1 = x0 + 32;
        float a0x=0.f,a0y=0.f,a0z=0.f,a0w=0.f;
        float a1x=0.f,a1y=0.f,a1z=0.f,a1w=0.f;
        #pragma unroll
        for (int k = 0; k < 32; k++) {
            float4 v0 = x0[k];
            float4 v1 = x1[k];
            a0x += w[4*k]*v0.x; a0y += w[4*k+1]*v0.y; a0z += w[4*k+2]*v0.z; a0w += w[4*k+3]*v0.w;
            a1x += w[4*k]*v1.x; a1y += w[4*k+1]*v1.y; a1z += w[4*k+2]*v1.z; a1w += w[4*k+3]*v1.w;
        }
        Xg[(size_t)r*GATES + j]     = bj + ((a0x+a0y)+(a0z+a0w));
        Xg[(size_t)(r+1)*GATES + j] = bj + ((a1x+a1y)+(a1z+a1w));
    }
}

// ---------------- K3: recurrence ----------------
__global__ __launch_bounds__(512, 2) void lstm_rec(const float* __restrict__ Xg,
                                                   const float* __restrict__ Whh_l,
                                                   float* __restrict__ hseq_l) {
    const int b = blockIdx.x;
    const int tid = threadIdx.x;
    const int kc = tid >> 7;     // wave-uniform k-chunk
    const int gg = tid & 127;
    const int lane = tid & 63;

    __shared__ __align__(16) float h_s[HID];
    __shared__ __align__(16) float part[4*GATES];

    float w[4][32];
    #pragma unroll
    for (int g = 0; g < 4; g++) {
        const float4* wr = (const float4*)(Whh_l + (size_t)(4*gg + g)*HID + kc*32);
        #pragma unroll
        for (int k4 = 0; k4 < 8; k4++) {
            float4 v = wr[k4];
            w[g][k4*4+0] = v.x; w[g][k4*4+1] = v.y; w[g][k4*4+2] = v.z; w[g][k4*4+3] = v.w;
        }
    }
    // force true register residency across the t-loop (see pin_vgpr comment)
    #pragma unroll
    for (int g = 0; g < 4; g++)
        #pragma unroll
        for (int k = 0; k < 32; k++) pin_vgpr(w[g][k]);

    const int useB = (kc & 2);
    const int base = __builtin_amdgcn_readfirstlane((kc & 1) << 5);

    float c = 0.f;
    if (tid < HID) h_s[tid] = 0.f;

    const float* xg_b = Xg + (size_t)b*TT*GATES;
    float* hout_b = hseq_l + (size_t)b*TT*HID;

    float xgc[4], xgn[4];
    if (tid < HID) {
        #pragma unroll
        for (int u = 0; u < 4; u++) xgc[u] = xg_b[u*HID + tid];
    }
    lds_barrier();

    for (int t = 0; t < TT; t++) {
        if (tid < HID && t + 1 < TT) {
            const float* p = xg_b + (size_t)(t+1)*GATES + tid;
            #pragma unroll
            for (int u = 0; u < 4; u++) xgn[u] = p[u*HID];
        }

        // co-op h read + readlane broadcast matvec
        {
            float hA = h_s[lane];
            float hB = h_s[64 + lane];
            float hsel = useB ? hB : hA;
            float a0 = 0.f, a1 = 0.f, a2 = 0.f, a3 = 0.f;
            #pragma unroll
            for (int k = 0; k < 32; k++) {
                float hv = bcast_lane(hsel, base + k);
                a0 += w[0][k]*hv; a1 += w[1][k]*hv; a2 += w[2][k]*hv; a3 += w[3][k]*hv;
            }
            float4 st = {a0, a1, a2, a3};
            *(float4*)(&part[kc*GATES + 4*gg]) = st;
        }
        lds_barrier();

        if (tid < HID) {
            float g4[4];
            #pragma unroll
            for (int u = 0; u < 4; u++) {
                float s = xgc[u];
                #pragma unroll
                for (int kcc = 0; kcc < 4; kcc++) s += part[kcc*GATES + u*HID + tid];
                g4[u] = s;
            }
            float si = fsig(g4[0]);
            float sf = fsig(g4[1]);
            float so = fsig(g4[3]);
            float tg = ftanh(g4[2]);
            c = sf*c + si*tg;
            float h = so*ftanh(c);
            h_s[tid] = h;
            hout_b[t*HID + tid] = h;    // fire-and-forget
        }
        lds_barrier();

        if (tid < HID) {
            #pragma unroll
            for (int u = 0; u < 4; u++) xgc[u] = xgn[u];
        }
    }
}

// ---------------- K4: final linear ----------------
__global__ void final_lin(const float* __restrict__ ws, const float* __restrict__ Wlin,
                          const float* __restrict__ blin, float* __restrict__ out) {
    const int b = blockIdx.x, l = threadIdx.x;  // 64 threads
    float acc = 0.f;
    #pragma unroll
    for (int u = 0; u < 8; u++) {
        int idx = u*64 + l;
        int layer = idx >> 7, k = idx & 127;
        const float* hs = ws + WS_HSEQ0 + (size_t)layer*HSEQ_SZ;
        acc += hs[((size_t)b*TT + (TT-1))*HID + k] * Wlin[idx];
    }
    #pragma unroll
    for (int d = 1; d < 64; d <<= 1) acc += __shfl_xor(acc, d);
    if (l == 0) out[b] = acc + blin[0];
}

extern "C" void kernel_launch(void* const* d_in, const int* in_sizes, int n_in,
                              void* d_out, int out_size, void* d_ws, size_t ws_size,
                              hipStream_t stream) {
    const float* x    = (const float*)d_in[0];
    const int*   adj  = (const int*)d_in[1];
    const float* W1   = (const float*)d_in[2];
    const float* a1   = (const float*)d_in[3];
    const float* W2   = (const float*)d_in[4];
    const float* a2   = (const float*)d_in[5];
    const float* Wih  = (const float*)d_in[6];
    const float* Whh  = (const float*)d_in[7];
    const float* bih  = (const float*)d_in[8];
    const float* bhh  = (const float*)d_in[9];
    const float* Wlin = (const float*)d_in[10];
    const float* blin = (const float*)d_in[11];
    const int*   site = (const int*)d_in[12];
    float* ws  = (float*)d_ws;
    float* out = (float*)d_out;

    prep1<<<1, 256, 0, stream>>>(W1, a1, W2, a2, bih, bhh, ws);
    prep2<<<FF, 128, 0, stream>>>(W1, W2, ws);
    prep3<<<35, 256, 0, stream>>>(W1, Wih, ws);
    gat_fused<<<dim3(TT, BB), 256, 0, stream>>>(x, adj, ws, ws + WS_XG, site);
    for (int l = 0; l < NLAYERS; l++) {
        if (l > 0) {
            lstm_ingemm<<<NROWS/16, 512, 0, stream>>>(ws + WS_HSEQ0 + (size_t)(l-1)*HSEQ_SZ,
                                                      Wih + (size_t)l*GATES*HID,
                                                      ws + WS_BSUM + l*GATES, ws + WS_XG);
        }
        lstm_rec<<<64, 512, 0, stream>>>(ws + WS_XG, Whh + (size_t)l*GATES*HID,
                                         ws + WS_HSEQ0 + (size_t)l*HSEQ_SZ);
    }
    final_lin<<<64, 64, 0, stream>>>(ws, Wlin, blin, out);
}

// Round 6
// 944.461 us; speedup vs baseline: 1.0218x; 1.0218x over previous
//
#include <hip/hip_runtime.h>
#include <hip/hip_bf16.h>

// Problem dims
#define BB 64
#define TT 168
#define NN 64
#define FF 17
#define HID 128
#define GATES 512   // 4*HID
#define NLAYERS 4
#define NROWS (BB*TT)   // 10752

// Workspace layout (float offsets)
#define WS_W1SRC 0
#define WS_W1DST 32
#define WS_W2SRC 64
#define WS_W2DST 192
#define WS_BSUM  320                    // 4*512 -> ends 2368
#define WS_WD    2560                   // 17 (pad 32): W1 @ (W2 @ a2dst)
#define WS_WSV   2592                   // 17 (pad 32): W1 @ (W2 @ a2src)
#define WS_W12   2624                   // 17*128 = 2176: W1 @ W2
#define WS_WXG0T 4800                   // 512*20 (17 used): (W12 @ Wih0^T)^T rows
#define WS_XG    1395712                // NROWS*512 = 5505024
#define WS_HSEQ0 6900736                // 4 buffers of NROWS*HID
#define HSEQ_SZ  1376256

// LDS-only barrier: s_waitcnt lgkmcnt(0) + raw s_barrier (no vmcnt drain).
__device__ __forceinline__ void lds_barrier() {
    __asm__ volatile("" ::: "memory");
    __builtin_amdgcn_s_waitcnt(0xc07f);
    __builtin_amdgcn_s_barrier();
    __asm__ volatile("" ::: "memory");
}

__device__ __forceinline__ float fsig(float x) {
    return __builtin_amdgcn_rcpf(1.f + __expf(-x));
}
__device__ __forceinline__ float ftanh(float x) {
    float e = __expf(2.f * x);
    return 1.f - 2.f * __builtin_amdgcn_rcpf(e + 1.f);
}
__device__ __forceinline__ float bcast_lane(float v, int lane) {
    return __int_as_float(__builtin_amdgcn_readlane(__float_as_int(v), lane));
}

// ---------------- prep1: attention projection vectors + bias sums ----------------
__global__ void prep1(const float* __restrict__ W1, const float* __restrict__ a1,
                      const float* __restrict__ W2, const float* __restrict__ a2,
                      const float* __restrict__ bih, const float* __restrict__ bhh,
                      float* __restrict__ ws) {
    int tid = threadIdx.x;
    if (tid < 34) {
        int f = tid % FF, half = tid / FF;
        float acc = 0.f;
        for (int o = 0; o < HID; o++) acc += W1[f*HID + o] * a1[half*HID + o];
        ws[(half ? WS_W1DST : WS_W1SRC) + f] = acc;
    }
    {
        int k = tid & 127, half = tid >> 7;
        float acc = 0.f;
        for (int o = 0; o < HID; o++) acc += W2[k*HID + o] * a2[half*HID + o];
        ws[(half ? WS_W2DST : WS_W2SRC) + k] = acc;
    }
    for (int idx = tid; idx < NLAYERS*GATES; idx += 256) ws[WS_BSUM + idx] = bih[idx] + bhh[idx];
}

// ---------------- prep2: W12 = W1 @ W2 (17 x 128) ----------------
__global__ void prep2(const float* __restrict__ W1, const float* __restrict__ W2,
                      float* __restrict__ ws) {
    int f = blockIdx.x, o = threadIdx.x;
    float acc = 0.f;
    for (int k = 0; k < HID; k++) acc += W1[f*HID + k] * W2[k*HID + o];
    ws[WS_W12 + f*HID + o] = acc;
}

// ---------------- prep3: WD/WSV (17 each) + WXG0T (512 x 17, stride 20) ----------------
__global__ void prep3(const float* __restrict__ W1, const float* __restrict__ Wih0,
                      float* __restrict__ ws) {
    int idx = blockIdx.x * 256 + threadIdx.x;
    if (idx < 17) {
        int f = idx;
        float acc = 0.f;
        for (int k = 0; k < HID; k++) acc += W1[f*HID + k] * ws[WS_W2DST + k];
        ws[WS_WD + f] = acc;
    } else if (idx < 34) {
        int f = idx - 17;
        float acc = 0.f;
        for (int k = 0; k < HID; k++) acc += W1[f*HID + k] * ws[WS_W2SRC + k];
        ws[WS_WSV + f] = acc;
    } else if (idx < 34 + GATES*FF) {
        int e = idx - 34;
        int j = e % GATES, f = e / GATES;   // f < 17
        float acc = 0.f;
        for (int o = 0; o < HID; o++) acc += ws[WS_W12 + f*HID + o] * Wih0[j*HID + o];
        ws[WS_WXG0T + j*20 + f] = acc;
    }
}

// ---------------- K1: fused GAT1 + GAT2(site) -> Xg layer-0 directly ----------------
struct __align__(16) GatSmem {
    float attn[64*68];       // P2 writes rows (stride 68), P3 reads
    float xsT[FF*64];        // [f][n]
    float xbarT[FF*68];      // [f][i], stride 68
    float src1[64], dst1[64], rinv[64], att2[64];
    float xbar2[20];
    float part_x[FF*8];      // P5a partials
    unsigned long long adjbits[64];
};
// ~28.5 KB -> 5 blocks/CU

__global__ __launch_bounds__(256) void gat_fused(const float* __restrict__ x, const int* __restrict__ adj,
                                                 const float* __restrict__ ws,
                                                 float* __restrict__ Xg, const int* __restrict__ site_ptr) {
    __shared__ GatSmem sm;
    const int tid = threadIdx.x;
    const int tt = blockIdx.x, bb = blockIdx.y;
    const int site = site_ptr[0];
    const int r = bb*TT + tt;
    const float* xblk = x + (size_t)r * (NN*FF);

    // P0: x transposed into LDS, adjacency bitmasks
    for (int idx = tid; idx < NN*FF; idx += 256) {
        int n = idx / FF, f = idx % FF;
        sm.xsT[f*64 + n] = xblk[idx];
    }
    {
        int w = tid >> 6, lane = tid & 63;
        for (int rr = w*16; rr < w*16 + 16; rr++) {
            int val = adj[rr*64 + lane];
            unsigned long long m = __ballot(val > 0);
            if (lane == 0) sm.adjbits[rr] = m | (1ull << rr);
        }
    }
    lds_barrier();

    // P1: src1/dst1 = x . (W1 @ a1-halves)
    if (tid < 128) {
        int n = tid & 63, half = tid >> 6;
        const float* wv = ws + (half ? WS_W1DST : WS_W1SRC);
        float acc = 0.f;
        #pragma unroll
        for (int f = 0; f < FF; f++) acc += sm.xsT[f*64 + n] * wv[f];
        if (half) sm.dst1[n] = acc; else sm.src1[n] = acc;
    }
    lds_barrier();

    // P2: attention logits -> exp -> attn rows
    {
        int q = tid & 3, i = tid >> 2;
        unsigned long long ab = sm.adjbits[i];
        float si = sm.src1[i];
        float v[16];
        float vmax = -1e30f;
        #pragma unroll
        for (int u = 0; u < 16; u++) {
            int jj = q*16 + u;
            float e = si + sm.dst1[jj];
            float lv = fmaxf(e, 0.2f*e);
            lv = ((ab >> jj) & 1ull) ? lv : -1e9f;
            v[u] = lv;
            vmax = fmaxf(vmax, lv);
        }
        vmax = fmaxf(vmax, __shfl_xor(vmax, 1, 4));
        vmax = fmaxf(vmax, __shfl_xor(vmax, 2, 4));
        float s = 0.f;
        float* arow = &sm.attn[i*68];
        #pragma unroll
        for (int w = 0; w < 4; w++) {
            float4 pv;
            pv.x = __expf(v[w*4+0] - vmax);
            pv.y = __expf(v[w*4+1] - vmax);
            pv.z = __expf(v[w*4+2] - vmax);
            pv.w = __expf(v[w*4+3] - vmax);
            s += (pv.x + pv.y) + (pv.z + pv.w);
            *(float4*)(arow + q*16 + w*4) = pv;
        }
        s += __shfl_xor(s, 1, 4);
        s += __shfl_xor(s, 2, 4);
        if (q == 0) sm.rinv[i] = 1.f / s;
    }
    lds_barrier();

    // P3: xbarT[f][i] = (P @ X)[i][f] * rinv
    {
        int i = tid & 63, q = tid >> 6;
        const float* arow = &sm.attn[i*68];
        float acc[5] = {0.f,0.f,0.f,0.f,0.f};
        const int nf = (q == 0) ? 5 : 4;
        for (int j4 = 0; j4 < 16; j4++) {
            float4 a4 = *(const float4*)(arow + j4*4);
            #pragma unroll
            for (int u = 0; u < 5; u++) {
                if (u < nf) {
                    int f = q + 4*u;
                    float4 x4 = *(const float4*)(&sm.xsT[f*64 + j4*4]);
                    acc[u] += a4.x*x4.x + a4.y*x4.y + a4.z*x4.z + a4.w*x4.w;
                }
            }
        }
        float ri = sm.rinv[i];
        #pragma unroll
        for (int u = 0; u < 5; u++) {
            if (u < nf) sm.xbarT[(q + 4*u)*68 + i] = acc[u] * ri;
        }
    }
    lds_barrier();

    // P4' (wave 0): dst2[j] = xbar[j].WD ; src2 = xbar[site].WSV ; softmax -> att2
    if (tid < 64) {
        int jj = tid;
        float d = 0.f, sp = 0.f;
        #pragma unroll
        for (int f = 0; f < FF; f++) {
            float xv = sm.xbarT[f*68 + jj];
            float xs = sm.xbarT[f*68 + site];
            d  += xv * ws[WS_WD + f];
            sp += xs * ws[WS_WSV + f];
        }
        unsigned long long ab = sm.adjbits[site];
        float e = sp + d;
        float lv = fmaxf(e, 0.2f*e);
        lv = ((ab >> jj) & 1ull) ? lv : -1e9f;
        float m = lv;
        #pragma unroll
        for (int dd = 1; dd < 64; dd <<= 1) m = fmaxf(m, __shfl_xor(m, dd));
        float p = __expf(lv - m);
        float s = p;
        #pragma unroll
        for (int dd = 1; dd < 64; dd <<= 1) s += __shfl_xor(s, dd);
        sm.att2[jj] = p / s;
    }
    lds_barrier();

    // P5a: xbar2 partials
    if (tid < FF*8) {
        int f = tid >> 3, c = tid & 7;
        float p = 0.f;
        #pragma unroll
        for (int u = 0; u < 8; u++) {
            int i = c*8 + u;
            p += sm.att2[i] * sm.xbarT[f*68 + i];
        }
        sm.part_x[f*8 + c] = p;
    }
    lds_barrier();

    // P5b: reduce xbar2
    if (tid < FF) {
        float s = 0.f;
        #pragma unroll
        for (int c = 0; c < 8; c++) s += sm.part_x[tid*8 + c];
        sm.xbar2[tid] = s;
    }
    lds_barrier();

    // P6': Xg0[r][j] = xbar2 . WXG0T[j] + bsum0[j]
    {
        float xb[FF];
        #pragma unroll
        for (int f = 0; f < FF; f++) xb[f] = sm.xbar2[f];
        #pragma unroll
        for (int half = 0; half < 2; half++) {
            int j = tid + half*256;
            const float4* wp = (const float4*)(ws + WS_WXG0T + j*20);
            float4 w0 = wp[0], w1 = wp[1], w2 = wp[2], w3 = wp[3];
            float wlast = ws[WS_WXG0T + j*20 + 16];
            float acc = ws[WS_BSUM + j];
            acc += w0.x*xb[0] + w0.y*xb[1] + w0.z*xb[2] + w0.w*xb[3];
            acc += w1.x*xb[4] + w1.y*xb[5] + w1.z*xb[6] + w1.w*xb[7];
            acc += w2.x*xb[8] + w2.y*xb[9] + w2.z*xb[10] + w2.w*xb[11];
            acc += w3.x*xb[12] + w3.y*xb[13] + w3.z*xb[14] + w3.w*xb[15];
            acc += wlast*xb[16];
            Xg[(size_t)r*GATES + j] = acc;
        }
    }
}

// ---------------- K2: input GEMM (layers 1-3) ----------------
__global__ __launch_bounds__(512, 1) void lstm_ingemm(const float* __restrict__ in_seq,
                                                      const float* __restrict__ Wih_l,
                                                      const float* __restrict__ bsum_l,
                                                      float* __restrict__ Xg) {
    const int j = threadIdx.x;
    float w[128];
    {
        const float4* wr = (const float4*)(Wih_l + j*HID);
        #pragma unroll
        for (int k = 0; k < 32; k++) {
            float4 v = wr[k];
            w[4*k] = v.x; w[4*k+1] = v.y; w[4*k+2] = v.z; w[4*k+3] = v.w;
        }
    }
    const float bj = bsum_l[j];
    const int r0 = blockIdx.x * 16;
    for (int rr = 0; rr < 16; rr += 2) {
        int r = r0 + rr;
        const float4* x0 = (const float4*)(in_seq + (size_t)r*HID);
        const float4* x1 = x0 + 32;
        float a0x=0.f,a0y=0.f,a0z=0.f,a0w=0.f;
        float a1x=0.f,a1y=0.f,a1z=0.f,a1w=0.f;
        #pragma unroll
        for (int k = 0; k < 32; k++) {
            float4 v0 = x0[k];
            float4 v1 = x1[k];
            a0x += w[4*k]*v0.x; a0y += w[4*k+1]*v0.y; a0z += w[4*k+2]*v0.z; a0w += w[4*k+3]*v0.w;
            a1x += w[4*k]*v1.x; a1y += w[4*k+1]*v1.y; a1z += w[4*k+2]*v1.z; a1w += w[4*k+3]*v1.w;
        }
        Xg[(size_t)r*GATES + j]     = bj + ((a0x+a0y)+(a0z+a0w));
        Xg[(size_t)(r+1)*GATES + j] = bj + ((a1x+a1y)+(a1z+a1w));
    }
}

// ---------------- K3: recurrence, single barrier per step ----------------
// Thread (kc=tid>>7, jj=tid&127) computes partials for gates {jj,128+jj,256+jj,384+jj}
// over k-chunk kc, written packed part[buf][kc][jj][0..3] (b128).
// h/c state is REGISTER-resident: lanes 0..31 of each wave own h[kc*32+lane]
// (wave pairs redundant) — exactly the 32 values that wave readlane-broadcasts
// in phase A. B(t) -> A(t+1) flows through registers (wave-synchronous), so only
// ONE barrier per step (A-writes -> B-reads); part[] is double-buffered so
// A(t+1) writes can't trample a straggler's B(t) reads.
__global__ __launch_bounds__(512, 1) void lstm_rec(const float* __restrict__ Xg,
                                                   const float* __restrict__ Whh_l,
                                                   float* __restrict__ hseq_l) {
    const int b = blockIdx.x;
    const int tid = threadIdx.x;
    const int lane = tid & 63;
    const int kc = tid >> 7;                 // 0..3, shared by wave pairs
    const int jj = tid & 127;                // A-partial output slot
    const int o = kc*32 + (lane & 31);       // B output owned by lanes<32
    const bool blane = (lane < 32);
    const bool storer = ((tid >> 6) & 1) == 0;   // first wave of each kc pair stores

    __shared__ __align__(16) float part[2][4][128][4];   // 16 KB

    float w[4][32];
    #pragma unroll
    for (int u = 0; u < 4; u++) {
        const float4* wr = (const float4*)(Whh_l + (size_t)(u*128 + jj)*HID + kc*32);
        #pragma unroll
        for (int k4 = 0; k4 < 8; k4++) {
            float4 v = wr[k4];
            w[u][k4*4+0] = v.x; w[u][k4*4+1] = v.y; w[u][k4*4+2] = v.z; w[u][k4*4+3] = v.w;
        }
    }

    const float* xg_b = Xg + (size_t)b*TT*GATES;
    float* hout_b = hseq_l + (size_t)b*TT*HID;

    float h_own = 0.f, c_own = 0.f;
    float xgc[4], xgn[4];
    if (blane) {
        #pragma unroll
        for (int u = 0; u < 4; u++) xgc[u] = xg_b[u*HID + o];
    }

    for (int t = 0; t < TT; t++) {
        // prefetch next step's xg (one full step of slack; never drained by barrier)
        if (blane && t + 1 < TT) {
            const float* p = xg_b + (size_t)(t+1)*GATES + o;
            #pragma unroll
            for (int u = 0; u < 4; u++) xgn[u] = p[u*HID];
        }

        // A: partial matvec; h[kc*32+k] broadcast from lane k's register
        float a0 = 0.f, a1 = 0.f, a2 = 0.f, a3 = 0.f;
        #pragma unroll
        for (int k = 0; k < 32; k++) {
            float hv = bcast_lane(h_own, k);
            a0 += w[0][k]*hv; a1 += w[1][k]*hv; a2 += w[2][k]*hv; a3 += w[3][k]*hv;
        }
        float4 st = {a0, a1, a2, a3};
        *(float4*)(&part[t & 1][kc][jj][0]) = st;

        lds_barrier();

        // B: lanes 0..31 of every wave update their owned output (pairs redundant)
        if (blane) {
            float4 s4 = {xgc[0], xgc[1], xgc[2], xgc[3]};
            #pragma unroll
            for (int kcc = 0; kcc < 4; kcc++) {
                float4 p = *(const float4*)(&part[t & 1][kcc][o][0]);
                s4.x += p.x; s4.y += p.y; s4.z += p.z; s4.w += p.w;
            }
            float si = fsig(s4.x), sf = fsig(s4.y), so = fsig(s4.w);
            float tg = ftanh(s4.z);
            c_own = sf*c_own + si*tg;
            h_own = so*ftanh(c_own);
            if (storer) hout_b[t*HID + o] = h_own;   // fire-and-forget
            #pragma unroll
            for (int u = 0; u < 4; u++) xgc[u] = xgn[u];
        }
    }
}

// ---------------- K4: final linear ----------------
__global__ void final_lin(const float* __restrict__ ws, const float* __restrict__ Wlin,
                          const float* __restrict__ blin, float* __restrict__ out) {
    const int b = blockIdx.x, l = threadIdx.x;  // 64 threads
    float acc = 0.f;
    #pragma unroll
    for (int u = 0; u < 8; u++) {
        int idx = u*64 + l;
        int layer = idx >> 7, k = idx & 127;
        const float* hs = ws + WS_HSEQ0 + (size_t)layer*HSEQ_SZ;
        acc += hs[((size_t)b*TT + (TT-1))*HID + k] * Wlin[idx];
    }
    #pragma unroll
    for (int d = 1; d < 64; d <<= 1) acc += __shfl_xor(acc, d);
    if (l == 0) out[b] = acc + blin[0];
}

extern "C" void kernel_launch(void* const* d_in, const int* in_sizes, int n_in,
                              void* d_out, int out_size, void* d_ws, size_t ws_size,
                              hipStream_t stream) {
    const float* x    = (const float*)d_in[0];
    const int*   adj  = (const int*)d_in[1];
    const float* W1   = (const float*)d_in[2];
    const float* a1   = (const float*)d_in[3];
    const float* W2   = (const float*)d_in[4];
    const float* a2   = (const float*)d_in[5];
    const float* Wih  = (const float*)d_in[6];
    const float* Whh  = (const float*)d_in[7];
    const float* bih  = (const float*)d_in[8];
    const float* bhh  = (const float*)d_in[9];
    const float* Wlin = (const float*)d_in[10];
    const float* blin = (const float*)d_in[11];
    const int*   site = (const int*)d_in[12];
    float* ws  = (float*)d_ws;
    float* out = (float*)d_out;

    prep1<<<1, 256, 0, stream>>>(W1, a1, W2, a2, bih, bhh, ws);
    prep2<<<FF, 128, 0, stream>>>(W1, W2, ws);
    prep3<<<35, 256, 0, stream>>>(W1, Wih, ws);
    gat_fused<<<dim3(TT, BB), 256, 0, stream>>>(x, adj, ws, ws + WS_XG, site);
    for (int l = 0; l < NLAYERS; l++) {
        if (l > 0) {
            lstm_ingemm<<<NROWS/16, 512, 0, stream>>>(ws + WS_HSEQ0 + (size_t)(l-1)*HSEQ_SZ,
                                                      Wih + (size_t)l*GATES*HID,
                                                      ws + WS_BSUM + l*GATES, ws + WS_XG);
        }
        lstm_rec<<<64, 512, 0, stream>>>(ws + WS_XG, Whh + (size_t)l*GATES*HID,
                                         ws + WS_HSEQ0 + (size_t)l*HSEQ_SZ);
    }
    final_lin<<<64, 64, 0, stream>>>(ws, Wlin, blin, out);
}